// Round 10
// baseline (591.999 us; speedup 1.0000x reference)
//
#include <hip/hip_runtime.h>

#define C 128
#define IN_A 1024
#define IN_V 512
#define NNODE 20000
#define NE 120000
#define NA 10000
#define NV 10000
#define EPSBN 1e-5f
#define NPAD 20032
#define EPAD 120064
#define NSTRIDE 20032

typedef __bf16 bf16_t;
typedef bf16_t bf16x8 __attribute__((ext_vector_type(8)));
typedef bf16_t bf16x2 __attribute__((ext_vector_type(2)));
typedef float f32x4 __attribute__((ext_vector_type(4)));
typedef unsigned int u32;

__device__ __forceinline__ f32x4 ld4(const float* p) {
    return *reinterpret_cast<const f32x4*>(p);
}
__device__ __forceinline__ f32x4 ld4nt(const float* p) {
    return __builtin_nontemporal_load(reinterpret_cast<const f32x4*>(p));
}
// bijective XCD-chunked swizzle over [0, n)
__device__ __forceinline__ int xcd_swz(int b, int n) {
    int q = n >> 3, r = n & 7;
    int x = b & 7, i = b >> 3;
    return (x < r ? x * (q + 1) : r * (q + 1) + (x - r) * q) + i;
}

struct PB {
    const float* x;
    const int* esrc; const int* edst; const int* edelta; const int* eself;
    const float* b0a; const float* b0v;
    const float* w0a; const float* w0v;
    const float* bn0; const float* bnn;
    const float* ecb1; const float* ecf1; const float* ecb2; const float* ecf2;
    const float* wh; const float* bh;
    float* out;
    bf16_t* W16; float* SBN; int* cnts; int* indeg; int* rowst; int* curs;
    int* psrc; int* pdst;
    bf16_t* G0; bf16_t* G1; bf16_t* msg;
};

// ---- prep: weights -> bf16, BN fold, indegree count ----
__global__ void prep0(PB P) {
    int b = blockIdx.x, t = threadIdx.x;
    if (b < 2304) {
        int i = b * 256 + t;   // < 589824 exactly
        float v;
        if (i < 131072) v = P.w0a[i];
        else if (i < 196608) v = P.w0v[i - 131072];
        else if (i < 458752) v = P.ecf1[i - 196608];
        else v = P.ecf2[i - 458752];
        P.W16[i] = (bf16_t)v;
    } else if (b < 2318) {
        int i = (b - 2304) * 256 + t;
        if (i >= 28 * 128) return;
        int pair = i >> 7, cc = i & 127;
        float gg, bb, mm, vv;
        if (pair == 0)      { gg = P.bn0[cc]; bb = P.bn0[128 + cc]; mm = P.bn0[256 + cc]; vv = P.bn0[384 + cc]; }
        else if (pair < 4)  { const float* q = P.bnn + (pair - 1) * 512;
                              gg = q[cc]; bb = q[128 + cc]; mm = q[256 + cc]; vv = q[384 + cc]; }
        else if (pair < 12) { const float* q = P.ecb1 + (pair - 4) * 1024;
                              gg = q[cc]; bb = q[256 + cc]; mm = q[512 + cc]; vv = q[768 + cc]; }
        else if (pair < 20) { const float* q = P.ecb1 + (pair - 12) * 1024 + 128;
                              gg = q[cc]; bb = q[256 + cc]; mm = q[512 + cc]; vv = q[768 + cc]; }
        else                { const float* q = P.ecb2 + (pair - 20) * 512;
                              gg = q[cc]; bb = q[128 + cc]; mm = q[256 + cc]; vv = q[384 + cc]; }
        float sv = gg * rsqrtf(vv + EPSBN);
        P.SBN[pair * 256 + cc] = sv;
        P.SBN[pair * 256 + 128 + cc] = bb - mm * sv;
    } else {
        int e = (b - 2318) * 256 + t;
        if (e >= NE) return;
        int d = P.edelta[e];
        int dn = P.edst[e];
        if (d < 1) atomicAdd(P.indeg + dn, 1);
        if (((d >= 1) && (d < 4)) || (P.eself[e] == 1)) atomicAdd(P.indeg + NSTRIDE + dn, 1);
    }
}

// ---- exclusive scan over indegrees (one block per half) ----
__global__ __launch_bounds__(1024) void scan_kernel(PB P) {
    __shared__ int sh[1024];
    int half = blockIdx.x;
    const int* in = P.indeg + half * NSTRIDE;
    int* rsw = P.rowst + half * NSTRIDE;
    int* cu = P.curs + half * NSTRIDE;
    int t = threadIdx.x;
    int base = t * 20;
    int s = 0;
    for (int i = 0; i < 20; i++) { int idx = base + i; if (idx < NNODE) s += in[idx]; }
    sh[t] = s;
    __syncthreads();
    for (int off = 1; off < 1024; off <<= 1) {
        int v = (t >= off) ? sh[t - off] : 0;
        __syncthreads();
        sh[t] += v;
        __syncthreads();
    }
    int run = sh[t] - s;
    for (int i = 0; i < 20; i++) {
        int idx = base + i;
        if (idx < NNODE) { int v = in[idx]; rsw[idx] = run; cu[idx] = run; run += v; }
    }
    if (t == 1023) { rsw[NNODE] = sh[1023]; P.cnts[half] = sh[1023]; }
}

// ---- combo0: layer0 (audio+video) + bn0/relu + av-heads ; scatter ----
__global__ __launch_bounds__(256) void combo0(PB P) {
    int b = blockIdx.x;
    if (b >= 314) {
        int e = (b - 314) * 256 + threadIdx.x;
        if (e >= NE) return;
        int d = P.edelta[e];
        int dn = P.edst[e], sn = P.esrc[e];
        if (d < 1) {
            int q = atomicAdd(P.curs + dn, 1);
            P.psrc[q] = sn; P.pdst[q] = dn;
        }
        if (((d >= 1) && (d < 4)) || (P.eself[e] == 1)) {
            int q = atomicAdd(P.curs + NSTRIDE + dn, 1);
            P.psrc[EPAD + q] = sn; P.pdst[EPAD + q] = dn;
        }
        return;
    }
    int wave = threadIdx.x >> 6, lane = threadIdx.x & 63;
    bool audio = b < 157;
    int tile = audio ? b : b - 157;
    const float* A = audio ? P.x : P.x + (size_t)NA * 2048 + 1024;
    const bf16_t* W = audio ? P.W16 : P.W16 + 131072;
    const float* bias = audio ? P.b0a : P.b0v;
    int K = audio ? IN_A : IN_V;
    int M = audio ? NA : NV;
    int nbase = audio ? 0 : NA;
    int hsel = audio ? 1 : 2;

    int m0 = tile * 64 + wave * 16;
    int arow = m0 + (lane & 15);
    int ar = arow < M ? arow : (M - 1);
    int ak = (lane >> 4) << 3;
    const float* Af = A + (size_t)ar * 2048 + ak;
    const bf16_t* Bp = W + (size_t)(lane & 15) * K + ak;

    f32x4 acc[8];
#pragma unroll
    for (int i = 0; i < 8; i++) acc[i] = (f32x4)(0.0f);
    for (int kk = 0; kk < K; kk += 32) {
        f32x4 v0 = ld4nt(Af + kk), v1 = ld4nt(Af + kk + 4);
        bf16x8 a;
#pragma unroll
        for (int j = 0; j < 4; j++) { a[j] = (bf16_t)v0[j]; a[4 + j] = (bf16_t)v1[j]; }
#pragma unroll
        for (int nt = 0; nt < 8; nt++) {
            bf16x8 bb = *reinterpret_cast<const bf16x8*>(Bp + (size_t)nt * 16 * K + kk);
            acc[nt] = __builtin_amdgcn_mfma_f32_16x16x32_bf16(a, bb, acc[nt], 0, 0, 0);
        }
    }
    int cb = lane & 15;
    float se[8], he[8], bs[8], w0[8], w1[8];
#pragma unroll
    for (int nt = 0; nt < 8; nt++) {
        int n = nt * 16 + cb;
        se[nt] = P.SBN[n]; he[nt] = P.SBN[128 + n]; bs[nt] = bias[n];
        w0[nt] = P.wh[hsel * 256 + n]; w1[nt] = P.wh[hsel * 256 + 128 + n];
    }
    int rbase = (lane >> 4) * 4;
#pragma unroll
    for (int j = 0; j < 4; j++) {
        int m = m0 + rbase + j;
        float hp0 = 0.f, hp1 = 0.f;
#pragma unroll
        for (int nt = 0; nt < 8; nt++) {
            int n = nt * 16 + cb;
            float v = fmaxf((acc[nt][j] + bs[nt]) * se[nt] + he[nt], 0.0f);
            if (m < M) P.G0[(size_t)(nbase + m) * C + n] = (bf16_t)v;
            hp0 += v * w0[nt]; hp1 += v * w1[nt];
        }
#pragma unroll
        for (int o = 8; o; o >>= 1) { hp0 += __shfl_xor(hp0, o); hp1 += __shfl_xor(hp1, o); }
        if (cb == 0 && m < M) {
            float* op = audio ? (P.out + 40000 + (size_t)m * 2)
                              : (P.out + 60000 + (size_t)m * 2);
            op[0] = hp0 + P.bh[hsel * 2 + 0];
            op[1] = hp1 + P.bh[hsel * 2 + 1];
        }
    }
}

// ---- fused edge kernel: one K=256 GEMM (U folded in) + bn2/relu -> LDS -> GEMM2 -> msg ----
// A-row = [relu(bn1a(Fd)), relu(bn1b(Fs-Fd))], B = full W1 [128][256]
__global__ __launch_bounds__(256, 4) void edge_k(PB P, int h) {
    __shared__ __align__(16) float hlds[4 * 2048];
    int half = h & 1;
    int Mreal = P.cnts[half];
    int tiles = (Mreal + 63) >> 6;
    if ((int)blockIdx.x >= tiles) return;
    int m0b = xcd_swz(blockIdx.x, tiles) * 64;
    const bf16_t* F = half ? P.G1 : P.G0;
    const int* psrc = P.psrc + (half ? EPAD : 0);
    const int* pdst = P.pdst + (half ? EPAD : 0);
    const bf16_t* B1 = P.W16 + 196608 + (size_t)h * 32768;        // full W1
    const bf16_t* B2 = P.W16 + 458752 + (size_t)h * 16384;
    const float* sA1 = P.SBN + (4 + h) * 256;                     // bn1a
    const float* sA2 = P.SBN + (12 + h) * 256;                    // bn1b
    const float* sE = P.SBN + (20 + h) * 256; const float* shE = sE + 128;

    int wave = threadIdx.x >> 6;
    int lane = threadIdx.x & 63;
    int m0 = m0b + wave * 16;
    int arow = m0 + (lane & 15);
    int ar = arow < Mreal ? arow : (Mreal - 1);
    int ak = (lane >> 4) << 3;

    const bf16_t* Fs = F + (size_t)psrc[ar] * C + ak;
    const bf16_t* Fd = F + (size_t)pdst[ar] * C + ak;
    const bf16_t* B1p = B1 + (size_t)(lane & 15) * 256 + ak;

    f32x4 acc[8];
#pragma unroll
    for (int i = 0; i < 8; i++) acc[i] = (f32x4)(0.0f);

    bf16x8 fd[4];
#pragma unroll
    for (int q = 0; q < 4; q++) fd[q] = *reinterpret_cast<const bf16x8*>(Fd + q * 32);

    // first half of K: relu(bn1a(Fd)) against W1 cols 0..127
#pragma unroll
    for (int q = 0; q < 4; q++) {
        int kk = q * 32;
        f32x4 s0 = ld4(sA1 + kk + ak), s1 = ld4(sA1 + kk + ak + 4);
        f32x4 h0 = ld4(sA1 + 128 + kk + ak), h1 = ld4(sA1 + 128 + kk + ak + 4);
        bf16x8 a;
#pragma unroll
        for (int j = 0; j < 4; j++) {
            a[j]     = (bf16_t)fmaxf((float)fd[q][j] * s0[j] + h0[j], 0.0f);
            a[4 + j] = (bf16_t)fmaxf((float)fd[q][4 + j] * s1[j] + h1[j], 0.0f);
        }
#pragma unroll
        for (int nt = 0; nt < 8; nt++) {
            bf16x8 bb = *reinterpret_cast<const bf16x8*>(B1p + (size_t)nt * 16 * 256 + kk);
            acc[nt] = __builtin_amdgcn_mfma_f32_16x16x32_bf16(a, bb, acc[nt], 0, 0, 0);
        }
    }
    // second half of K: relu(bn1b(Fs-Fd)) against W1 cols 128..255
#pragma unroll
    for (int q = 0; q < 4; q++) {
        int kk = q * 32;
        bf16x8 s8 = *reinterpret_cast<const bf16x8*>(Fs + kk);
        f32x4 s0 = ld4(sA2 + kk + ak), s1 = ld4(sA2 + kk + ak + 4);
        f32x4 h0 = ld4(sA2 + 128 + kk + ak), h1 = ld4(sA2 + 128 + kk + ak + 4);
        bf16x8 a;
#pragma unroll
        for (int j = 0; j < 4; j++) {
            a[j]     = (bf16_t)fmaxf(((float)s8[j] - (float)fd[q][j]) * s0[j] + h0[j], 0.0f);
            a[4 + j] = (bf16_t)fmaxf(((float)s8[4 + j] - (float)fd[q][4 + j]) * s1[j] + h1[j], 0.0f);
        }
#pragma unroll
        for (int nt = 0; nt < 8; nt++) {
            bf16x8 bb = *reinterpret_cast<const bf16x8*>(B1p + (size_t)nt * 16 * 256 + 128 + kk);
            acc[nt] = __builtin_amdgcn_mfma_f32_16x16x32_bf16(a, bb, acc[nt], 0, 0, 0);
        }
    }

    int cb = lane & 15;
    float se[8], he[8];
#pragma unroll
    for (int nt = 0; nt < 8; nt++) { se[nt] = sE[nt * 16 + cb]; he[nt] = shE[nt * 16 + cb]; }
    int rbase = (lane >> 4) * 4;
    float* wl = hlds + wave * 2048;
#pragma unroll
    for (int j = 0; j < 4; j++) {
        int r = rbase + j;
        int sw = (r & 7) << 2;
#pragma unroll
        for (int nt = 0; nt < 8; nt++) {
            int n = nt * 16 + cb;
            wl[(r * 128 + n) ^ sw] = fmaxf(acc[nt][j] * se[nt] + he[nt], 0.0f);
        }
    }
    // no __syncthreads — wave reads back only its own hlds slice
    const bf16_t* B2p = B2 + (size_t)(lane & 15) * C + ak;
#pragma unroll
    for (int i = 0; i < 8; i++) acc[i] = (f32x4)(0.0f);
    int rr = lane & 15;
    int swz = (rr & 7) << 2;
    const float* rl = hlds + wave * 2048;
#pragma unroll
    for (int kk = 0; kk < C; kk += 32) {
        int c0 = kk + ak;
        f32x4 v0 = *reinterpret_cast<const f32x4*>(rl + ((rr * 128 + c0) ^ swz));
        f32x4 v1 = *reinterpret_cast<const f32x4*>(rl + ((rr * 128 + c0 + 4) ^ swz));
        bf16x8 a;
#pragma unroll
        for (int j = 0; j < 4; j++) { a[j] = (bf16_t)v0[j]; a[4 + j] = (bf16_t)v1[j]; }
#pragma unroll
        for (int nt = 0; nt < 8; nt++) {
            bf16x8 bb = *reinterpret_cast<const bf16x8*>(B2p + (size_t)nt * 16 * C + kk);
            acc[nt] = __builtin_amdgcn_mfma_f32_16x16x32_bf16(a, bb, acc[nt], 0, 0, 0);
        }
    }
#pragma unroll
    for (int j = 0; j < 4; j++) {
        int m = m0 + rbase + j;
        if (m < Mreal) {
            bf16_t* op = P.msg + (size_t)m * C;
#pragma unroll
            for (int nt = 0; nt < 8; nt++) op[nt * 16 + cb] = (bf16_t)acc[nt][j];
        }
    }
}

// ---- agg + post (no K1): 16 nodes/block, 8 waves, wave = 2 nodes ----
__global__ __launch_bounds__(512) void aggk1(PB P, int h) {
    int half = h & 1, p = h >> 1;
    int tile = xcd_swz(blockIdx.x, 1250);
    int wave = threadIdx.x >> 6;
    int lane = threadIdx.x & 63;
    const int* rs = P.rowst + half * NSTRIDE;
    const u32* msgu = (const u32*)P.msg;
    int c = lane * 2;

    float sn0 = 0.f, sn1 = 0.f, hn0 = 0.f, hn1 = 0.f;
    if (half && p < 3) {
        const float* q = P.SBN + (1 + p) * 256;
        sn0 = q[c]; sn1 = q[c + 1]; hn0 = q[128 + c]; hn1 = q[128 + c + 1];
    }
    float w0c0 = 0.f, w0c1 = 0.f, w1c0 = 0.f, w1c1 = 0.f;
    if (h == 7) { w0c0 = P.wh[c]; w0c1 = P.wh[c + 1]; w1c0 = P.wh[128 + c]; w1c1 = P.wh[129 + c]; }

#pragma unroll
    for (int i = 0; i < 2; i++) {
        int n = tile * 16 + wave * 2 + i;
        if (n >= NNODE) continue;
        int p0 = rs[n], p1 = rs[n + 1];
        float v0 = -INFINITY, v1 = -INFINITY;
        int q = p0;
        for (; q + 1 < p1; q += 2) {
            u32 u0 = msgu[(size_t)q * 64 + lane];
            u32 u1 = msgu[(size_t)(q + 1) * 64 + lane];
            v0 = fmaxf(v0, __uint_as_float(u0 << 16));
            v1 = fmaxf(v1, __uint_as_float(u0 & 0xffff0000u));
            v0 = fmaxf(v0, __uint_as_float(u1 << 16));
            v1 = fmaxf(v1, __uint_as_float(u1 & 0xffff0000u));
        }
        if (q < p1) {
            u32 u = msgu[(size_t)q * 64 + lane];
            v0 = fmaxf(v0, __uint_as_float(u << 16));
            v1 = fmaxf(v1, __uint_as_float(u & 0xffff0000u));
        }
        if (p1 == p0) { v0 = 0.f; v1 = 0.f; }
        if (h == 7) {
            bf16x2 r2 = *((const bf16x2*)(P.G0 + (size_t)n * C) + lane);
            v0 += (float)r2[0]; v1 += (float)r2[1];
            float q0 = v0 * w0c0 + v1 * w0c1;
            float q1 = v0 * w1c0 + v1 * w1c1;
#pragma unroll
            for (int o = 32; o; o >>= 1) { q0 += __shfl_down(q0, o); q1 += __shfl_down(q1, o); }
            if (lane == 0) {
                P.out[(size_t)n * 2 + 0] = q0 + P.bh[0];
                P.out[(size_t)n * 2 + 1] = q1 + P.bh[1];
            }
        } else if (!half) {
            bf16x2 w; w[0] = (bf16_t)v0; w[1] = (bf16_t)v1;
            *((bf16x2*)(P.G1 + (size_t)n * C) + lane) = w;
        } else {
            float r0 = 0.f, r1 = 0.f;
            if (p >= 1) {
                bf16x2 r2 = *((const bf16x2*)(P.G0 + (size_t)n * C) + lane);
                r0 = (float)r2[0]; r1 = (float)r2[1];
            }
            float g0v = fmaxf((v0 + r0) * sn0 + hn0, 0.0f);
            float g1v = fmaxf((v1 + r1) * sn1 + hn1, 0.0f);
            bf16x2 w; w[0] = (bf16_t)g0v; w[1] = (bf16_t)g1v;
            *((bf16x2*)(P.G0 + (size_t)n * C) + lane) = w;   // in-place update
        }
    }
}

extern "C" void kernel_launch(void* const* d_in, const int* in_sizes, int n_in,
                              void* d_out, int out_size, void* d_ws, size_t ws_size,
                              hipStream_t stream) {
    PB P;
    P.x      = (const float*)d_in[0];
    const int* eidx = (const int*)d_in[1];
    P.esrc   = eidx;
    P.edst   = eidx + NE;
    P.edelta = (const int*)d_in[2];
    P.eself  = (const int*)d_in[3];
    P.w0a    = (const float*)d_in[5];
    P.b0a    = (const float*)d_in[6];
    P.w0v    = (const float*)d_in[7];
    P.b0v    = (const float*)d_in[8];
    P.bn0    = (const float*)d_in[9];
    P.bnn    = (const float*)d_in[10];
    P.ecb1   = (const float*)d_in[11];
    P.ecf1   = (const float*)d_in[12];
    P.ecb2   = (const float*)d_in[13];
    P.ecf2   = (const float*)d_in[14];
    P.wh     = (const float*)d_in[15];
    P.bh     = (const float*)d_in[16];
    P.out    = (float*)d_out;

    char* wsb = (char*)d_ws;
    size_t off = 0;
    auto take = [&](size_t bytes) -> char* {
        char* p = wsb + off;
        off = (off + bytes + 255) & ~(size_t)255;
        return p;
    };
    P.W16   = (bf16_t*)take(589824 * 2);
    P.SBN   = (float*)take(28 * 256 * 4);
    P.cnts  = (int*)take(256);
    P.indeg = (int*)take(2 * NSTRIDE * 4);
    P.rowst = (int*)take((2 * NSTRIDE + 64) * 4);
    P.curs  = (int*)take(2 * NSTRIDE * 4);
    P.psrc  = (int*)take(2 * (size_t)EPAD * 4);
    P.pdst  = (int*)take(2 * (size_t)EPAD * 4);
    P.G0    = (bf16_t*)take((size_t)NPAD * C * 2);
    P.G1    = (bf16_t*)take((size_t)NPAD * C * 2);
    P.msg   = (bf16_t*)take((size_t)EPAD * C * 2);
    (void)ws_size; (void)in_sizes; (void)n_in; (void)out_size;

    hipMemsetAsync(P.indeg, 0, 2 * NSTRIDE * 4, stream);
    prep0<<<2787, 256, 0, stream>>>(P);
    scan_kernel<<<2, 1024, 0, stream>>>(P);
    combo0<<<783, 256, 0, stream>>>(P);
    for (int h = 0; h < 8; h++) {
        edge_k<<<EPAD / 64, 256, 0, stream>>>(P, h);
        aggk1<<<1250, 512, 0, stream>>>(P, h);
    }
}

// Round 11
// 543.835 us; speedup vs baseline: 1.0886x; 1.0886x over previous
//
#include <hip/hip_runtime.h>

#define C 128
#define IN_A 1024
#define IN_V 512
#define NNODE 20000
#define NE 120000
#define NA 10000
#define NV 10000
#define EPSBN 1e-5f
#define NPAD 20032
#define EPAD 120064
#define NSTRIDE 20032

typedef __bf16 bf16_t;
typedef bf16_t bf16x8 __attribute__((ext_vector_type(8)));
typedef bf16_t bf16x2 __attribute__((ext_vector_type(2)));
typedef float f32x4 __attribute__((ext_vector_type(4)));
typedef unsigned int u32;

__device__ __forceinline__ f32x4 ld4(const float* p) {
    return *reinterpret_cast<const f32x4*>(p);
}
__device__ __forceinline__ f32x4 ld4nt(const float* p) {
    return __builtin_nontemporal_load(reinterpret_cast<const f32x4*>(p));
}
// bijective XCD-chunked swizzle over [0, n)
__device__ __forceinline__ int xcd_swz(int b, int n) {
    int q = n >> 3, r = n & 7;
    int x = b & 7, i = b >> 3;
    return (x < r ? x * (q + 1) : r * (q + 1) + (x - r) * q) + i;
}

struct PB {
    const float* x;
    const int* esrc; const int* edst; const int* edelta; const int* eself;
    const float* b0a; const float* b0v;
    const float* w0a; const float* w0v;
    const float* bn0; const float* bnn;
    const float* ecb1; const float* ecf1; const float* ecb2; const float* ecf2;
    const float* wh; const float* bh;
    float* out;
    bf16_t* W16; float* SBN; int* cnts; int* indeg; int* rowst; int* curs;
    int* psrc; int* pdst;
    float* U; bf16_t* G0; bf16_t* G1; bf16_t* msg;
};

// ---- prep: weights -> bf16, BN fold, indegree count ----
__global__ void prep0(PB P) {
    int b = blockIdx.x, t = threadIdx.x;
    if (b < 2304) {
        int i = b * 256 + t;   // < 589824 exactly
        float v;
        if (i < 131072) v = P.w0a[i];
        else if (i < 196608) v = P.w0v[i - 131072];
        else if (i < 458752) v = P.ecf1[i - 196608];
        else v = P.ecf2[i - 458752];
        P.W16[i] = (bf16_t)v;
    } else if (b < 2318) {
        int i = (b - 2304) * 256 + t;
        if (i >= 28 * 128) return;
        int pair = i >> 7, cc = i & 127;
        float gg, bb, mm, vv;
        if (pair == 0)      { gg = P.bn0[cc]; bb = P.bn0[128 + cc]; mm = P.bn0[256 + cc]; vv = P.bn0[384 + cc]; }
        else if (pair < 4)  { const float* q = P.bnn + (pair - 1) * 512;
                              gg = q[cc]; bb = q[128 + cc]; mm = q[256 + cc]; vv = q[384 + cc]; }
        else if (pair < 12) { const float* q = P.ecb1 + (pair - 4) * 1024;
                              gg = q[cc]; bb = q[256 + cc]; mm = q[512 + cc]; vv = q[768 + cc]; }
        else if (pair < 20) { const float* q = P.ecb1 + (pair - 12) * 1024 + 128;
                              gg = q[cc]; bb = q[256 + cc]; mm = q[512 + cc]; vv = q[768 + cc]; }
        else                { const float* q = P.ecb2 + (pair - 20) * 512;
                              gg = q[cc]; bb = q[128 + cc]; mm = q[256 + cc]; vv = q[384 + cc]; }
        float sv = gg * rsqrtf(vv + EPSBN);
        P.SBN[pair * 256 + cc] = sv;
        P.SBN[pair * 256 + 128 + cc] = bb - mm * sv;
    } else {
        int e = (b - 2318) * 256 + t;
        if (e >= NE) return;
        int d = P.edelta[e];
        int dn = P.edst[e];
        if (d < 1) atomicAdd(P.indeg + dn, 1);
        if (((d >= 1) && (d < 4)) || (P.eself[e] == 1)) atomicAdd(P.indeg + NSTRIDE + dn, 1);
    }
}

// ---- exclusive scan over indegrees (one block per half) ----
__global__ __launch_bounds__(1024) void scan_kernel(PB P) {
    __shared__ int sh[1024];
    int half = blockIdx.x;
    const int* in = P.indeg + half * NSTRIDE;
    int* rsw = P.rowst + half * NSTRIDE;
    int* cu = P.curs + half * NSTRIDE;
    int t = threadIdx.x;
    int base = t * 20;
    int s = 0;
    for (int i = 0; i < 20; i++) { int idx = base + i; if (idx < NNODE) s += in[idx]; }
    sh[t] = s;
    __syncthreads();
    for (int off = 1; off < 1024; off <<= 1) {
        int v = (t >= off) ? sh[t - off] : 0;
        __syncthreads();
        sh[t] += v;
        __syncthreads();
    }
    int run = sh[t] - s;
    for (int i = 0; i < 20; i++) {
        int idx = base + i;
        if (idx < NNODE) { int v = in[idx]; rsw[idx] = run; cu[idx] = run; run += v; }
    }
    if (t == 1023) { rsw[NNODE] = sh[1023]; P.cnts[half] = sh[1023]; }
}

// ---- combo0: layer0 (audio+video) + bn0/relu + av-heads + U(0) GEMM ; scatter ----
__global__ __launch_bounds__(256) void combo0(PB P) {
    __shared__ __align__(16) char smem[16384];
    int b = blockIdx.x;
    if (b >= 314) {
        int e = (b - 314) * 256 + threadIdx.x;
        if (e >= NE) return;
        int d = P.edelta[e];
        int dn = P.edst[e], sn = P.esrc[e];
        if (d < 1) {
            int q = atomicAdd(P.curs + dn, 1);
            P.psrc[q] = sn; P.pdst[q] = dn;
        }
        if (((d >= 1) && (d < 4)) || (P.eself[e] == 1)) {
            int q = atomicAdd(P.curs + NSTRIDE + dn, 1);
            P.psrc[EPAD + q] = sn; P.pdst[EPAD + q] = dn;
        }
        return;
    }
    int wave = threadIdx.x >> 6, lane = threadIdx.x & 63;
    bool audio = b < 157;
    int tile = audio ? b : b - 157;
    const float* A = audio ? P.x : P.x + (size_t)NA * 2048 + 1024;
    const bf16_t* W = audio ? P.W16 : P.W16 + 131072;
    const float* bias = audio ? P.b0a : P.b0v;
    int K = audio ? IN_A : IN_V;
    int M = audio ? NA : NV;
    int nbase = audio ? 0 : NA;
    int hsel = audio ? 1 : 2;

    int m0 = tile * 64 + wave * 16;
    int arow = m0 + (lane & 15);
    int ar = arow < M ? arow : (M - 1);
    int ak = (lane >> 4) << 3;
    const float* Af = A + (size_t)ar * 2048 + ak;
    const bf16_t* Bp = W + (size_t)(lane & 15) * K + ak;

    f32x4 acc[8];
#pragma unroll
    for (int i = 0; i < 8; i++) acc[i] = (f32x4)(0.0f);
    for (int kk = 0; kk < K; kk += 32) {
        f32x4 v0 = ld4nt(Af + kk), v1 = ld4nt(Af + kk + 4);
        bf16x8 a;
#pragma unroll
        for (int j = 0; j < 4; j++) { a[j] = (bf16_t)v0[j]; a[4 + j] = (bf16_t)v1[j]; }
#pragma unroll
        for (int nt = 0; nt < 8; nt++) {
            bf16x8 bb = *reinterpret_cast<const bf16x8*>(Bp + (size_t)nt * 16 * K + kk);
            acc[nt] = __builtin_amdgcn_mfma_f32_16x16x32_bf16(a, bb, acc[nt], 0, 0, 0);
        }
    }
    int cb = lane & 15;
    float se[8], he[8], bs[8], w0[8], w1[8], s1[8], t1[8];
#pragma unroll
    for (int nt = 0; nt < 8; nt++) {
        int n = nt * 16 + cb;
        se[nt] = P.SBN[n]; he[nt] = P.SBN[128 + n]; bs[nt] = bias[n];
        w0[nt] = P.wh[hsel * 256 + n]; w1[nt] = P.wh[hsel * 256 + 128 + n];
        s1[nt] = P.SBN[4 * 256 + n]; t1[nt] = P.SBN[4 * 256 + 128 + n];
    }
    int rbase = (lane >> 4) * 4;
#pragma unroll
    for (int j = 0; j < 4; j++) {
        int m = m0 + rbase + j;
        int r = wave * 16 + rbase + j;
        float hp0 = 0.f, hp1 = 0.f;
#pragma unroll
        for (int nt = 0; nt < 8; nt++) {
            int n = nt * 16 + cb;
            float v = fmaxf((acc[nt][j] + bs[nt]) * se[nt] + he[nt], 0.0f);
            if (m < M) P.G0[(size_t)(nbase + m) * C + n] = (bf16_t)v;
            hp0 += v * w0[nt]; hp1 += v * w1[nt];
            float av = fmaxf(v * s1[nt] + t1[nt], 0.0f);
            int byte = (r * 256 + 2 * n) ^ ((r & 7) << 4);
            *reinterpret_cast<bf16_t*>(smem + byte) = (bf16_t)av;
        }
#pragma unroll
        for (int o = 8; o; o >>= 1) { hp0 += __shfl_xor(hp0, o); hp1 += __shfl_xor(hp1, o); }
        if (cb == 0 && m < M) {
            float* op = audio ? (P.out + 40000 + (size_t)m * 2)
                              : (P.out + 60000 + (size_t)m * 2);
            op[0] = hp0 + P.bh[hsel * 2 + 0];
            op[1] = hp1 + P.bh[hsel * 2 + 1];
        }
    }
    // no __syncthreads — each wave reads back only its own smem rows
    // U(0) GEMM from LDS a-frags, B = W1a(0)
    const bf16_t* B2p = P.W16 + 196608 + (size_t)(lane & 15) * 256 + ak;
#pragma unroll
    for (int i = 0; i < 8; i++) acc[i] = (f32x4)(0.0f);
    int rr = wave * 16 + (lane & 15);
#pragma unroll
    for (int kk = 0; kk < C; kk += 32) {
        int byte = (rr * 256 + 2 * (ak + kk)) ^ ((rr & 7) << 4);
        bf16x8 a = *reinterpret_cast<const bf16x8*>(smem + byte);
#pragma unroll
        for (int nt = 0; nt < 8; nt++) {
            bf16x8 bb = *reinterpret_cast<const bf16x8*>(B2p + (size_t)nt * 16 * 256 + kk);
            acc[nt] = __builtin_amdgcn_mfma_f32_16x16x32_bf16(a, bb, acc[nt], 0, 0, 0);
        }
    }
#pragma unroll
    for (int j = 0; j < 4; j++) {
        int m = m0 + rbase + j;
        if (m >= M) continue;
#pragma unroll
        for (int nt = 0; nt < 8; nt++)
            P.U[(size_t)(nbase + m) * C + nt * 16 + cb] = acc[nt][j];
    }
}

// ---- fused edge kernel (low-VGPR): staged a-frags, 2-pass GEMMs, bf16 LDS ----
__global__ __launch_bounds__(256, 5) void edge_k(PB P, int h) {
    __shared__ __align__(16) char hb[4][4096];   // per-wave 16x128 bf16, swizzled (16KB)
    int half = h & 1;
    int Mreal = P.cnts[half];
    int tiles = (Mreal + 63) >> 6;
    if ((int)blockIdx.x >= tiles) return;
    int m0b = xcd_swz(blockIdx.x, tiles) * 64;
    const bf16_t* F = half ? P.G1 : P.G0;
    const int* psrc = P.psrc + (half ? EPAD : 0);
    const int* pdst = P.pdst + (half ? EPAD : 0);
    const bf16_t* B1 = P.W16 + 196608 + (size_t)h * 32768 + 128;   // bn1b half of W1, ldb 256
    const bf16_t* B2 = P.W16 + 458752 + (size_t)h * 16384;
    const float* sA = P.SBN + (12 + h) * 256; const float* shA = sA + 128;
    const float* sE = P.SBN + (20 + h) * 256; const float* shE = sE + 128;

    int wave = threadIdx.x >> 6;
    int lane = threadIdx.x & 63;
    int m0 = m0b + wave * 16;
    int arow = m0 + (lane & 15);
    int ar = arow < Mreal ? arow : (Mreal - 1);
    int ak = (lane >> 4) << 3;
    int cb = lane & 15;
    int rbase = (lane >> 4) * 4;

    const bf16_t* Fs = F + (size_t)psrc[ar] * C + ak;
    const bf16_t* Fd = F + (size_t)pdst[ar] * C + ak;

    // edge dst rows for the mid-epilogue U-gather (hoisted)
    int dj[4];
#pragma unroll
    for (int j = 0; j < 4; j++) {
        int m = m0 + rbase + j;
        dj[j] = pdst[m < Mreal ? m : (Mreal - 1)];
    }

    // stage gathers and build A-fragments once (K=128 -> 4 frags, 16 VGPR)
    bf16x8 av[4];
    {
        bf16x8 fs[4], fdv[4];
#pragma unroll
        for (int q = 0; q < 4; q++) {
            fs[q]  = *reinterpret_cast<const bf16x8*>(Fs + q * 32);
            fdv[q] = *reinterpret_cast<const bf16x8*>(Fd + q * 32);
        }
#pragma unroll
        for (int q = 0; q < 4; q++) {
            int kk = q * 32;
            f32x4 s0 = ld4(sA + kk + ak), s1 = ld4(sA + kk + ak + 4);
            f32x4 h0 = ld4(shA + kk + ak), h1 = ld4(shA + kk + ak + 4);
            bf16x8 a;
#pragma unroll
            for (int j = 0; j < 4; j++) {
                a[j]     = (bf16_t)fmaxf(((float)fs[q][j] - (float)fdv[q][j]) * s0[j] + h0[j], 0.0f);
                a[4 + j] = (bf16_t)fmaxf(((float)fs[q][4 + j] - (float)fdv[q][4 + j]) * s1[j] + h1[j], 0.0f);
            }
            av[q] = a;
        }
    }

    char* wl = hb[wave];

    // GEMM1 + mid-epilogue (U add, bn2, relu -> bf16 LDS), 2 passes x 4 col-tiles
#pragma unroll
    for (int pass = 0; pass < 2; pass++) {
        f32x4 acc[4];
#pragma unroll
        for (int i = 0; i < 4; i++) acc[i] = (f32x4)(0.0f);
#pragma unroll
        for (int q = 0; q < 4; q++) {
            int kk = q * 32;
#pragma unroll
            for (int nt = 0; nt < 4; nt++) {
                const bf16_t* bp = B1 + (size_t)((pass * 4 + nt) * 16 + cb) * 256 + kk + ak;
                bf16x8 bb = *reinterpret_cast<const bf16x8*>(bp);
                acc[nt] = __builtin_amdgcn_mfma_f32_16x16x32_bf16(av[q], bb, acc[nt], 0, 0, 0);
            }
        }
#pragma unroll
        for (int j = 0; j < 4; j++) {
            const float* Ur = P.U + (size_t)dj[j] * C + pass * 64;
            int r = rbase + j;
#pragma unroll
            for (int nt = 0; nt < 4; nt++) {
                int n = nt * 16 + cb;
                int gn = pass * 64 + n;
                float v = acc[nt][j] + Ur[n];
                float hv = fmaxf(v * sE[gn] + shE[gn], 0.0f);
                int byte = (r * 256 + 2 * gn) ^ ((r & 7) << 4);
                *reinterpret_cast<bf16_t*>(wl + byte) = (bf16_t)hv;
            }
        }
    }
    // no barrier: wave-private LDS slice
    // GEMM2: A = H row (bf16 LDS), 2 passes x 4 col-tiles
    int rr = lane & 15;
#pragma unroll
    for (int pass = 0; pass < 2; pass++) {
        f32x4 acc[4];
#pragma unroll
        for (int i = 0; i < 4; i++) acc[i] = (f32x4)(0.0f);
#pragma unroll
        for (int q = 0; q < 4; q++) {
            int kk = q * 32;
            int byte = (rr * 256 + 2 * (kk + ak)) ^ ((rr & 7) << 4);
            bf16x8 a = *reinterpret_cast<const bf16x8*>(wl + byte);
#pragma unroll
            for (int nt = 0; nt < 4; nt++) {
                const bf16_t* bp = B2 + (size_t)((pass * 4 + nt) * 16 + cb) * C + kk + ak;
                bf16x8 bb = *reinterpret_cast<const bf16x8*>(bp);
                acc[nt] = __builtin_amdgcn_mfma_f32_16x16x32_bf16(a, bb, acc[nt], 0, 0, 0);
            }
        }
#pragma unroll
        for (int j = 0; j < 4; j++) {
            int m = m0 + rbase + j;
            if (m < Mreal) {
                bf16_t* op = P.msg + (size_t)m * C + pass * 64;
#pragma unroll
                for (int nt = 0; nt < 4; nt++) op[nt * 16 + cb] = (bf16_t)acc[nt][j];
            }
        }
    }
}

// ---- fused agg + post + next-layer K1 (U): 16 nodes/block, 8 waves ----
__global__ __launch_bounds__(512) void aggk1(PB P, int h) {
    __shared__ __align__(16) char smem[4096];
    int half = h & 1, p = h >> 1;
    int tile = xcd_swz(blockIdx.x, 1250);
    int wave = threadIdx.x >> 6;
    int lane = threadIdx.x & 63;
    const int* rs = P.rowst + half * NSTRIDE;
    const u32* msgu = (const u32*)P.msg;
    int c = lane * 2;

    const float* s1a = P.SBN + (5 + h) * 256;
    float s1c0 = s1a[c], s1c1 = s1a[c + 1], h1c0 = s1a[128 + c], h1c1 = s1a[128 + c + 1];
    float sn0 = 0.f, sn1 = 0.f, hn0 = 0.f, hn1 = 0.f;
    if (half && p < 3) {
        const float* q = P.SBN + (1 + p) * 256;
        sn0 = q[c]; sn1 = q[c + 1]; hn0 = q[128 + c]; hn1 = q[128 + c + 1];
    }
    float w0c0 = 0.f, w0c1 = 0.f, w1c0 = 0.f, w1c1 = 0.f;
    if (h == 7) { w0c0 = P.wh[c]; w0c1 = P.wh[c + 1]; w1c0 = P.wh[128 + c]; w1c1 = P.wh[129 + c]; }

#pragma unroll
    for (int i = 0; i < 2; i++) {
        int n = tile * 16 + wave * 2 + i;
        int r = wave * 2 + i;
        float a0 = 0.f, a1 = 0.f;
        if (n < NNODE) {
            int p0 = rs[n], p1 = rs[n + 1];
            float v0 = -INFINITY, v1 = -INFINITY;
            int q = p0;
            for (; q + 1 < p1; q += 2) {
                u32 u0 = msgu[(size_t)q * 64 + lane];
                u32 u1 = msgu[(size_t)(q + 1) * 64 + lane];
                v0 = fmaxf(v0, __uint_as_float(u0 << 16));
                v1 = fmaxf(v1, __uint_as_float(u0 & 0xffff0000u));
                v0 = fmaxf(v0, __uint_as_float(u1 << 16));
                v1 = fmaxf(v1, __uint_as_float(u1 & 0xffff0000u));
            }
            if (q < p1) {
                u32 u = msgu[(size_t)q * 64 + lane];
                v0 = fmaxf(v0, __uint_as_float(u << 16));
                v1 = fmaxf(v1, __uint_as_float(u & 0xffff0000u));
            }
            if (p1 == p0) { v0 = 0.f; v1 = 0.f; }
            if (h == 7) {
                bf16x2 r2 = *((const bf16x2*)(P.G0 + (size_t)n * C) + lane);
                v0 += (float)r2[0]; v1 += (float)r2[1];
                float q0 = v0 * w0c0 + v1 * w0c1;
                float q1 = v0 * w1c0 + v1 * w1c1;
#pragma unroll
                for (int o = 32; o; o >>= 1) { q0 += __shfl_down(q0, o); q1 += __shfl_down(q1, o); }
                if (lane == 0) {
                    P.out[(size_t)n * 2 + 0] = q0 + P.bh[0];
                    P.out[(size_t)n * 2 + 1] = q1 + P.bh[1];
                }
            } else {
                float g0v, g1v;
                if (!half) {
                    g0v = v0; g1v = v1;
                    bf16x2 w; w[0] = (bf16_t)g0v; w[1] = (bf16_t)g1v;
                    *((bf16x2*)(P.G1 + (size_t)n * C) + lane) = w;
                } else {
                    float r0 = 0.f, r1 = 0.f;
                    if (p >= 1) {
                        bf16x2 r2 = *((const bf16x2*)(P.G0 + (size_t)n * C) + lane);
                        r0 = (float)r2[0]; r1 = (float)r2[1];
                    }
                    g0v = fmaxf((v0 + r0) * sn0 + hn0, 0.0f);
                    g1v = fmaxf((v1 + r1) * sn1 + hn1, 0.0f);
                    bf16x2 w; w[0] = (bf16_t)g0v; w[1] = (bf16_t)g1v;
                    *((bf16x2*)(P.G0 + (size_t)n * C) + lane) = w;   // in-place update
                }
                a0 = fmaxf(g0v * s1c0 + h1c0, 0.0f);
                a1 = fmaxf(g1v * s1c1 + h1c1, 0.0f);
            }
        }
        if (h < 7) {
            int byte = (r * 256 + lane * 4) ^ ((r & 7) << 4);
            bf16x2 t; t[0] = (bf16_t)a0; t[1] = (bf16_t)a1;
            *reinterpret_cast<bf16x2*>(smem + byte) = t;
        }
    }
    if (h == 7) return;
    __syncthreads();
    // K1 of layer h+1: A = 16-row LDS tile (shared), each wave one 16-col n-tile
    const bf16_t* B = P.W16 + 196608 + (size_t)(h + 1) * 32768;
    int cb = lane & 15;
    int ak = (lane >> 4) << 3;
    const bf16_t* Bp = B + (size_t)(wave * 16 + cb) * 256 + ak;
    f32x4 acc = (f32x4)(0.0f);
#pragma unroll
    for (int kk = 0; kk < C; kk += 32) {
        int byte = (cb * 256 + 2 * (ak + kk)) ^ ((cb & 7) << 4);
        bf16x8 a = *reinterpret_cast<const bf16x8*>(smem + byte);
        bf16x8 bb = *reinterpret_cast<const bf16x8*>(Bp + kk);
        acc = __builtin_amdgcn_mfma_f32_16x16x32_bf16(a, bb, acc, 0, 0, 0);
    }
#pragma unroll
    for (int j = 0; j < 4; j++) {
        int m = tile * 16 + (lane >> 4) * 4 + j;
        if (m < NNODE) P.U[(size_t)m * C + wave * 16 + cb] = acc[j];
    }
}

extern "C" void kernel_launch(void* const* d_in, const int* in_sizes, int n_in,
                              void* d_out, int out_size, void* d_ws, size_t ws_size,
                              hipStream_t stream) {
    PB P;
    P.x      = (const float*)d_in[0];
    const int* eidx = (const int*)d_in[1];
    P.esrc   = eidx;
    P.edst   = eidx + NE;
    P.edelta = (const int*)d_in[2];
    P.eself  = (const int*)d_in[3];
    P.w0a    = (const float*)d_in[5];
    P.b0a    = (const float*)d_in[6];
    P.w0v    = (const float*)d_in[7];
    P.b0v    = (const float*)d_in[8];
    P.bn0    = (const float*)d_in[9];
    P.bnn    = (const float*)d_in[10];
    P.ecb1   = (const float*)d_in[11];
    P.ecf1   = (const float*)d_in[12];
    P.ecb2   = (const float*)d_in[13];
    P.ecf2   = (const float*)d_in[14];
    P.wh     = (const float*)d_in[15];
    P.bh     = (const float*)d_in[16];
    P.out    = (float*)d_out;

    char* wsb = (char*)d_ws;
    size_t off = 0;
    auto take = [&](size_t bytes) -> char* {
        char* p = wsb + off;
        off = (off + bytes + 255) & ~(size_t)255;
        return p;
    };
    P.W16   = (bf16_t*)take(589824 * 2);
    P.SBN   = (float*)take(28 * 256 * 4);
    P.cnts  = (int*)take(256);
    P.indeg = (int*)take(2 * NSTRIDE * 4);
    P.rowst = (int*)take((2 * NSTRIDE + 64) * 4);
    P.curs  = (int*)take(2 * NSTRIDE * 4);
    P.psrc  = (int*)take(2 * (size_t)EPAD * 4);
    P.pdst  = (int*)take(2 * (size_t)EPAD * 4);
    P.U     = (float*)take((size_t)NPAD * C * 4);
    P.G0    = (bf16_t*)take((size_t)NPAD * C * 2);
    P.G1    = (bf16_t*)take((size_t)NPAD * C * 2);
    P.msg   = (bf16_t*)take((size_t)EPAD * C * 2);
    (void)ws_size; (void)in_sizes; (void)n_in; (void)out_size;

    hipMemsetAsync(P.indeg, 0, 2 * NSTRIDE * 4, stream);
    prep0<<<2787, 256, 0, stream>>>(P);
    scan_kernel<<<2, 1024, 0, stream>>>(P);
    combo0<<<783, 256, 0, stream>>>(P);
    for (int h = 0; h < 8; h++) {
        edge_k<<<EPAD / 64, 256, 0, stream>>>(P, h);
        aggk1<<<1250, 512, 0, stream>>>(P, h);
    }
}

// Round 12
// 522.638 us; speedup vs baseline: 1.1327x; 1.0406x over previous
//
#include <hip/hip_runtime.h>

#define C 128
#define IN_A 1024
#define IN_V 512
#define NNODE 20000
#define NE 120000
#define NA 10000
#define NV 10000
#define EPSBN 1e-5f
#define NPAD 20032
#define EPAD 120064
#define NSTRIDE 20032

typedef __bf16 bf16_t;
typedef bf16_t bf16x8 __attribute__((ext_vector_type(8)));
typedef bf16_t bf16x2 __attribute__((ext_vector_type(2)));
typedef float f32x4 __attribute__((ext_vector_type(4)));
typedef unsigned int u32;

__device__ __forceinline__ f32x4 ld4(const float* p) {
    return *reinterpret_cast<const f32x4*>(p);
}
__device__ __forceinline__ f32x4 ld4nt(const float* p) {
    return __builtin_nontemporal_load(reinterpret_cast<const f32x4*>(p));
}
// bijective XCD-chunked swizzle over [0, n)
__device__ __forceinline__ int xcd_swz(int b, int n) {
    int q = n >> 3, r = n & 7;
    int x = b & 7, i = b >> 3;
    return (x < r ? x * (q + 1) : r * (q + 1) + (x - r) * q) + i;
}

struct PB {
    const float* x;
    const int* esrc; const int* edst; const int* edelta; const int* eself;
    const float* b0a; const float* b0v;
    const float* w0a; const float* w0v;
    const float* bn0; const float* bnn;
    const float* ecb1; const float* ecf1; const float* ecb2; const float* ecf2;
    const float* wh; const float* bh;
    float* out;
    bf16_t* W16; float* SBN; int* cnts; int* indeg; int* rowst; int* curs;
    int* psrc; int* pdst;
    float* U; bf16_t* G0; bf16_t* G1; bf16_t* msg;
};

// ---- prep: weights -> bf16, BN fold, indegree count ----
__global__ void prep0(PB P) {
    int b = blockIdx.x, t = threadIdx.x;
    if (b < 2304) {
        int i = b * 256 + t;   // < 589824 exactly
        float v;
        if (i < 131072) v = P.w0a[i];
        else if (i < 196608) v = P.w0v[i - 131072];
        else if (i < 458752) v = P.ecf1[i - 196608];
        else v = P.ecf2[i - 458752];
        P.W16[i] = (bf16_t)v;
    } else if (b < 2318) {
        int i = (b - 2304) * 256 + t;
        if (i >= 28 * 128) return;
        int pair = i >> 7, cc = i & 127;
        float gg, bb, mm, vv;
        if (pair == 0)      { gg = P.bn0[cc]; bb = P.bn0[128 + cc]; mm = P.bn0[256 + cc]; vv = P.bn0[384 + cc]; }
        else if (pair < 4)  { const float* q = P.bnn + (pair - 1) * 512;
                              gg = q[cc]; bb = q[128 + cc]; mm = q[256 + cc]; vv = q[384 + cc]; }
        else if (pair < 12) { const float* q = P.ecb1 + (pair - 4) * 1024;
                              gg = q[cc]; bb = q[256 + cc]; mm = q[512 + cc]; vv = q[768 + cc]; }
        else if (pair < 20) { const float* q = P.ecb1 + (pair - 12) * 1024 + 128;
                              gg = q[cc]; bb = q[256 + cc]; mm = q[512 + cc]; vv = q[768 + cc]; }
        else                { const float* q = P.ecb2 + (pair - 20) * 512;
                              gg = q[cc]; bb = q[128 + cc]; mm = q[256 + cc]; vv = q[384 + cc]; }
        float sv = gg * rsqrtf(vv + EPSBN);
        P.SBN[pair * 256 + cc] = sv;
        P.SBN[pair * 256 + 128 + cc] = bb - mm * sv;
    } else {
        int e = (b - 2318) * 256 + t;
        if (e >= NE) return;
        int d = P.edelta[e];
        int dn = P.edst[e];
        if (d < 1) atomicAdd(P.indeg + dn, 1);
        if (((d >= 1) && (d < 4)) || (P.eself[e] == 1)) atomicAdd(P.indeg + NSTRIDE + dn, 1);
    }
}

// ---- exclusive scan over indegrees (one block per half) ----
__global__ __launch_bounds__(1024) void scan_kernel(PB P) {
    __shared__ int sh[1024];
    int half = blockIdx.x;
    const int* in = P.indeg + half * NSTRIDE;
    int* rsw = P.rowst + half * NSTRIDE;
    int* cu = P.curs + half * NSTRIDE;
    int t = threadIdx.x;
    int base = t * 20;
    int s = 0;
    for (int i = 0; i < 20; i++) { int idx = base + i; if (idx < NNODE) s += in[idx]; }
    sh[t] = s;
    __syncthreads();
    for (int off = 1; off < 1024; off <<= 1) {
        int v = (t >= off) ? sh[t - off] : 0;
        __syncthreads();
        sh[t] += v;
        __syncthreads();
    }
    int run = sh[t] - s;
    for (int i = 0; i < 20; i++) {
        int idx = base + i;
        if (idx < NNODE) { int v = in[idx]; rsw[idx] = run; cu[idx] = run; run += v; }
    }
    if (t == 1023) { rsw[NNODE] = sh[1023]; P.cnts[half] = sh[1023]; }
}

// ---- combo0: layer0 (audio+video) + bn0/relu + av-heads + U(0) GEMM ; scatter ----
__global__ __launch_bounds__(256) void combo0(PB P) {
    __shared__ __align__(16) char smem[16384];
    int b = blockIdx.x;
    if (b >= 314) {
        int e = (b - 314) * 256 + threadIdx.x;
        if (e >= NE) return;
        int d = P.edelta[e];
        int dn = P.edst[e], sn = P.esrc[e];
        if (d < 1) {
            int q = atomicAdd(P.curs + dn, 1);
            P.psrc[q] = sn; P.pdst[q] = dn;
        }
        if (((d >= 1) && (d < 4)) || (P.eself[e] == 1)) {
            int q = atomicAdd(P.curs + NSTRIDE + dn, 1);
            P.psrc[EPAD + q] = sn; P.pdst[EPAD + q] = dn;
        }
        return;
    }
    int wave = threadIdx.x >> 6, lane = threadIdx.x & 63;
    bool audio = b < 157;
    int tile = audio ? b : b - 157;
    const float* A = audio ? P.x : P.x + (size_t)NA * 2048 + 1024;
    const bf16_t* W = audio ? P.W16 : P.W16 + 131072;
    const float* bias = audio ? P.b0a : P.b0v;
    int K = audio ? IN_A : IN_V;
    int M = audio ? NA : NV;
    int nbase = audio ? 0 : NA;
    int hsel = audio ? 1 : 2;

    int m0 = tile * 64 + wave * 16;
    int arow = m0 + (lane & 15);
    int ar = arow < M ? arow : (M - 1);
    int ak = (lane >> 4) << 3;
    const float* Af = A + (size_t)ar * 2048 + ak;
    const bf16_t* Bp = W + (size_t)(lane & 15) * K + ak;

    f32x4 acc[8];
#pragma unroll
    for (int i = 0; i < 8; i++) acc[i] = (f32x4)(0.0f);
#pragma unroll 8
    for (int kk = 0; kk < K; kk += 32) {
        f32x4 v0 = ld4nt(Af + kk), v1 = ld4nt(Af + kk + 4);
        bf16x8 a;
#pragma unroll
        for (int j = 0; j < 4; j++) { a[j] = (bf16_t)v0[j]; a[4 + j] = (bf16_t)v1[j]; }
#pragma unroll
        for (int nt = 0; nt < 8; nt++) {
            bf16x8 bb = *reinterpret_cast<const bf16x8*>(Bp + (size_t)nt * 16 * K + kk);
            acc[nt] = __builtin_amdgcn_mfma_f32_16x16x32_bf16(a, bb, acc[nt], 0, 0, 0);
        }
    }
    int cb = lane & 15;
    float se[8], he[8], bs[8], w0[8], w1[8], s1[8], t1[8];
#pragma unroll
    for (int nt = 0; nt < 8; nt++) {
        int n = nt * 16 + cb;
        se[nt] = P.SBN[n]; he[nt] = P.SBN[128 + n]; bs[nt] = bias[n];
        w0[nt] = P.wh[hsel * 256 + n]; w1[nt] = P.wh[hsel * 256 + 128 + n];
        s1[nt] = P.SBN[4 * 256 + n]; t1[nt] = P.SBN[4 * 256 + 128 + n];
    }
    int rbase = (lane >> 4) * 4;
#pragma unroll
    for (int j = 0; j < 4; j++) {
        int m = m0 + rbase + j;
        int r = wave * 16 + rbase + j;
        float hp0 = 0.f, hp1 = 0.f;
#pragma unroll
        for (int nt = 0; nt < 8; nt++) {
            int n = nt * 16 + cb;
            float v = fmaxf((acc[nt][j] + bs[nt]) * se[nt] + he[nt], 0.0f);
            if (m < M) P.G0[(size_t)(nbase + m) * C + n] = (bf16_t)v;
            hp0 += v * w0[nt]; hp1 += v * w1[nt];
            float av = fmaxf(v * s1[nt] + t1[nt], 0.0f);
            int byte = (r * 256 + 2 * n) ^ ((r & 7) << 4);
            *reinterpret_cast<bf16_t*>(smem + byte) = (bf16_t)av;
        }
#pragma unroll
        for (int o = 8; o; o >>= 1) { hp0 += __shfl_xor(hp0, o); hp1 += __shfl_xor(hp1, o); }
        if (cb == 0 && m < M) {
            float* op = audio ? (P.out + 40000 + (size_t)m * 2)
                              : (P.out + 60000 + (size_t)m * 2);
            op[0] = hp0 + P.bh[hsel * 2 + 0];
            op[1] = hp1 + P.bh[hsel * 2 + 1];
        }
    }
    // no __syncthreads — each wave reads back only its own smem rows
    // U(0) GEMM from LDS a-frags, B = W1a(0)
    const bf16_t* B2p = P.W16 + 196608 + (size_t)(lane & 15) * 256 + ak;
#pragma unroll
    for (int i = 0; i < 8; i++) acc[i] = (f32x4)(0.0f);
    int rr = wave * 16 + (lane & 15);
#pragma unroll
    for (int kk = 0; kk < C; kk += 32) {
        int byte = (rr * 256 + 2 * (ak + kk)) ^ ((rr & 7) << 4);
        bf16x8 a = *reinterpret_cast<const bf16x8*>(smem + byte);
#pragma unroll
        for (int nt = 0; nt < 8; nt++) {
            bf16x8 bb = *reinterpret_cast<const bf16x8*>(B2p + (size_t)nt * 16 * 256 + kk);
            acc[nt] = __builtin_amdgcn_mfma_f32_16x16x32_bf16(a, bb, acc[nt], 0, 0, 0);
        }
    }
#pragma unroll
    for (int j = 0; j < 4; j++) {
        int m = m0 + rbase + j;
        if (m >= M) continue;
#pragma unroll
        for (int nt = 0; nt < 8; nt++)
            P.U[(size_t)(nbase + m) * C + nt * 16 + cb] = acc[nt][j];
    }
}

// ---- fused edge kernel: U-gather hoisted before GEMM1 (latency hidden under MFMA) ----
__global__ __launch_bounds__(256) void edge_k(PB P, int h) {
    __shared__ __align__(16) float hlds[4 * 2048];
    int half = h & 1;
    int Mreal = P.cnts[half];
    int tiles = (Mreal + 63) >> 6;
    if ((int)blockIdx.x >= tiles) return;
    int m0b = xcd_swz(blockIdx.x, tiles) * 64;
    const bf16_t* F = half ? P.G1 : P.G0;
    const int* psrc = P.psrc + (half ? EPAD : 0);
    const int* pdst = P.pdst + (half ? EPAD : 0);
    const bf16_t* B1 = P.W16 + 196608 + (size_t)h * 32768 + 128;
    const bf16_t* B2 = P.W16 + 458752 + (size_t)h * 16384;
    const float* sA = P.SBN + (12 + h) * 256; const float* shA = sA + 128;
    const float* sE = P.SBN + (20 + h) * 256; const float* shE = sE + 128;

    int wave = threadIdx.x >> 6;
    int lane = threadIdx.x & 63;
    int m0 = m0b + wave * 16;
    int arow = m0 + (lane & 15);
    int ar = arow < Mreal ? arow : (Mreal - 1);
    int ak = (lane >> 4) << 3;
    int cb = lane & 15;
    int rbase = (lane >> 4) * 4;

    const bf16_t* Fs = F + (size_t)psrc[ar] * C + ak;
    const bf16_t* Fd = F + (size_t)pdst[ar] * C + ak;
    const bf16_t* B1p = B1 + (size_t)(lane & 15) * 256 + ak;

    // hoisted U-gather: addresses known up-front; loads overlap GEMM1
    float uvv[4][8];
    {
        int dj[4];
#pragma unroll
        for (int j = 0; j < 4; j++) {
            int m = m0 + rbase + j;
            dj[j] = pdst[m < Mreal ? m : (Mreal - 1)];
        }
#pragma unroll
        for (int j = 0; j < 4; j++) {
            const float* Ur = P.U + (size_t)dj[j] * C + cb;
#pragma unroll
            for (int nt = 0; nt < 8; nt++) uvv[j][nt] = Ur[nt * 16];
        }
    }

    f32x4 acc[8];
#pragma unroll
    for (int i = 0; i < 8; i++) acc[i] = (f32x4)(0.0f);
#pragma unroll
    for (int kk = 0; kk < C; kk += 32) {
        bf16x8 s8 = *reinterpret_cast<const bf16x8*>(Fs + kk);
        bf16x8 d8 = *reinterpret_cast<const bf16x8*>(Fd + kk);
        f32x4 s0 = ld4(sA + kk + ak), s1 = ld4(sA + kk + ak + 4);
        f32x4 h0 = ld4(shA + kk + ak), h1 = ld4(shA + kk + ak + 4);
        bf16x8 a;
#pragma unroll
        for (int j = 0; j < 4; j++) {
            float t0 = fmaxf(((float)s8[j] - (float)d8[j]) * s0[j] + h0[j], 0.0f);
            float t1 = fmaxf(((float)s8[4 + j] - (float)d8[4 + j]) * s1[j] + h1[j], 0.0f);
            a[j] = (bf16_t)t0; a[4 + j] = (bf16_t)t1;
        }
#pragma unroll
        for (int nt = 0; nt < 8; nt++) {
            bf16x8 bb = *reinterpret_cast<const bf16x8*>(B1p + (size_t)nt * 16 * 256 + kk);
            acc[nt] = __builtin_amdgcn_mfma_f32_16x16x32_bf16(a, bb, acc[nt], 0, 0, 0);
        }
    }
    float se[8], he[8];
#pragma unroll
    for (int nt = 0; nt < 8; nt++) { se[nt] = sE[nt * 16 + cb]; he[nt] = shE[nt * 16 + cb]; }
    float* wl = hlds + wave * 2048;
#pragma unroll
    for (int j = 0; j < 4; j++) {
        int r = rbase + j;
        int sw = (r & 7) << 2;
#pragma unroll
        for (int nt = 0; nt < 8; nt++) {
            int n = nt * 16 + cb;
            float v = acc[nt][j] + uvv[j][nt];
            wl[(r * 128 + n) ^ sw] = fmaxf(v * se[nt] + he[nt], 0.0f);
        }
    }
    // no __syncthreads — wave reads back only its own hlds slice
    const bf16_t* B2p = B2 + (size_t)(lane & 15) * C + ak;
#pragma unroll
    for (int i = 0; i < 8; i++) acc[i] = (f32x4)(0.0f);
    int rr = lane & 15;
    int swz = (rr & 7) << 2;
    const float* rl = hlds + wave * 2048;
#pragma unroll
    for (int kk = 0; kk < C; kk += 32) {
        int c0 = kk + ak;
        f32x4 v0 = *reinterpret_cast<const f32x4*>(rl + ((rr * 128 + c0) ^ swz));
        f32x4 v1 = *reinterpret_cast<const f32x4*>(rl + ((rr * 128 + c0 + 4) ^ swz));
        bf16x8 a;
#pragma unroll
        for (int j = 0; j < 4; j++) { a[j] = (bf16_t)v0[j]; a[4 + j] = (bf16_t)v1[j]; }
#pragma unroll
        for (int nt = 0; nt < 8; nt++) {
            bf16x8 bb = *reinterpret_cast<const bf16x8*>(B2p + (size_t)nt * 16 * C + kk);
            acc[nt] = __builtin_amdgcn_mfma_f32_16x16x32_bf16(a, bb, acc[nt], 0, 0, 0);
        }
    }
#pragma unroll
    for (int j = 0; j < 4; j++) {
        int m = m0 + rbase + j;
        if (m < Mreal) {
            bf16_t* op = P.msg + (size_t)m * C;
#pragma unroll
            for (int nt = 0; nt < 8; nt++) op[nt * 16 + cb] = (bf16_t)acc[nt][j];
        }
    }
}

// ---- fused agg + post + next-layer K1 (U): 16 nodes/block, 8 waves ----
__global__ __launch_bounds__(512) void aggk1(PB P, int h) {
    __shared__ __align__(16) char smem[4096];
    int half = h & 1, p = h >> 1;
    int tile = xcd_swz(blockIdx.x, 1250);
    int wave = threadIdx.x >> 6;
    int lane = threadIdx.x & 63;
    const int* rs = P.rowst + half * NSTRIDE;
    const u32* msgu = (const u32*)P.msg;
    int c = lane * 2;

    const float* s1a = P.SBN + (5 + h) * 256;
    float s1c0 = s1a[c], s1c1 = s1a[c + 1], h1c0 = s1a[128 + c], h1c1 = s1a[128 + c + 1];
    float sn0 = 0.f, sn1 = 0.f, hn0 = 0.f, hn1 = 0.f;
    if (half && p < 3) {
        const float* q = P.SBN + (1 + p) * 256;
        sn0 = q[c]; sn1 = q[c + 1]; hn0 = q[128 + c]; hn1 = q[128 + c + 1];
    }
    float w0c0 = 0.f, w0c1 = 0.f, w1c0 = 0.f, w1c1 = 0.f;
    if (h == 7) { w0c0 = P.wh[c]; w0c1 = P.wh[c + 1]; w1c0 = P.wh[128 + c]; w1c1 = P.wh[129 + c]; }

#pragma unroll
    for (int i = 0; i < 2; i++) {
        int n = tile * 16 + wave * 2 + i;
        int r = wave * 2 + i;
        float a0 = 0.f, a1 = 0.f;
        if (n < NNODE) {
            int p0 = rs[n], p1 = rs[n + 1];
            float v0 = -INFINITY, v1 = -INFINITY;
            int q = p0;
            for (; q + 1 < p1; q += 2) {
                u32 u0 = msgu[(size_t)q * 64 + lane];
                u32 u1 = msgu[(size_t)(q + 1) * 64 + lane];
                v0 = fmaxf(v0, __uint_as_float(u0 << 16));
                v1 = fmaxf(v1, __uint_as_float(u0 & 0xffff0000u));
                v0 = fmaxf(v0, __uint_as_float(u1 << 16));
                v1 = fmaxf(v1, __uint_as_float(u1 & 0xffff0000u));
            }
            if (q < p1) {
                u32 u = msgu[(size_t)q * 64 + lane];
                v0 = fmaxf(v0, __uint_as_float(u << 16));
                v1 = fmaxf(v1, __uint_as_float(u & 0xffff0000u));
            }
            if (p1 == p0) { v0 = 0.f; v1 = 0.f; }
            if (h == 7) {
                bf16x2 r2 = *((const bf16x2*)(P.G0 + (size_t)n * C) + lane);
                v0 += (float)r2[0]; v1 += (float)r2[1];
                float q0 = v0 * w0c0 + v1 * w0c1;
                float q1 = v0 * w1c0 + v1 * w1c1;
#pragma unroll
                for (int o = 32; o; o >>= 1) { q0 += __shfl_down(q0, o); q1 += __shfl_down(q1, o); }
                if (lane == 0) {
                    P.out[(size_t)n * 2 + 0] = q0 + P.bh[0];
                    P.out[(size_t)n * 2 + 1] = q1 + P.bh[1];
                }
            } else {
                float g0v, g1v;
                if (!half) {
                    g0v = v0; g1v = v1;
                    bf16x2 w; w[0] = (bf16_t)g0v; w[1] = (bf16_t)g1v;
                    *((bf16x2*)(P.G1 + (size_t)n * C) + lane) = w;
                } else {
                    float r0 = 0.f, r1 = 0.f;
                    if (p >= 1) {
                        bf16x2 r2 = *((const bf16x2*)(P.G0 + (size_t)n * C) + lane);
                        r0 = (float)r2[0]; r1 = (float)r2[1];
                    }
                    g0v = fmaxf((v0 + r0) * sn0 + hn0, 0.0f);
                    g1v = fmaxf((v1 + r1) * sn1 + hn1, 0.0f);
                    bf16x2 w; w[0] = (bf16_t)g0v; w[1] = (bf16_t)g1v;
                    *((bf16x2*)(P.G0 + (size_t)n * C) + lane) = w;   // in-place update
                }
                a0 = fmaxf(g0v * s1c0 + h1c0, 0.0f);
                a1 = fmaxf(g1v * s1c1 + h1c1, 0.0f);
            }
        }
        if (h < 7) {
            int byte = (r * 256 + lane * 4) ^ ((r & 7) << 4);
            bf16x2 t; t[0] = (bf16_t)a0; t[1] = (bf16_t)a1;
            *reinterpret_cast<bf16x2*>(smem + byte) = t;
        }
    }
    if (h == 7) return;
    __syncthreads();
    // K1 of layer h+1: A = 16-row LDS tile (shared), each wave one 16-col n-tile
    const bf16_t* B = P.W16 + 196608 + (size_t)(h + 1) * 32768;
    int cb = lane & 15;
    int ak = (lane >> 4) << 3;
    const bf16_t* Bp = B + (size_t)(wave * 16 + cb) * 256 + ak;
    f32x4 acc = (f32x4)(0.0f);
#pragma unroll
    for (int kk = 0; kk < C; kk += 32) {
        int byte = (cb * 256 + 2 * (ak + kk)) ^ ((cb & 7) << 4);
        bf16x8 a = *reinterpret_cast<const bf16x8*>(smem + byte);
        bf16x8 bb = *reinterpret_cast<const bf16x8*>(Bp + kk);
        acc = __builtin_amdgcn_mfma_f32_16x16x32_bf16(a, bb, acc, 0, 0, 0);
    }
#pragma unroll
    for (int j = 0; j < 4; j++) {
        int m = tile * 16 + (lane >> 4) * 4 + j;
        if (m < NNODE) P.U[(size_t)m * C + wave * 16 + cb] = acc[j];
    }
}

extern "C" void kernel_launch(void* const* d_in, const int* in_sizes, int n_in,
                              void* d_out, int out_size, void* d_ws, size_t ws_size,
                              hipStream_t stream) {
    PB P;
    P.x      = (const float*)d_in[0];
    const int* eidx = (const int*)d_in[1];
    P.esrc   = eidx;
    P.edst   = eidx + NE;
    P.edelta = (const int*)d_in[2];
    P.eself  = (const int*)d_in[3];
    P.w0a    = (const float*)d_in[5];
    P.b0a    = (const float*)d_in[6];
    P.w0v    = (const float*)d_in[7];
    P.b0v    = (const float*)d_in[8];
    P.bn0    = (const float*)d_in[9];
    P.bnn    = (const float*)d_in[10];
    P.ecb1   = (const float*)d_in[11];
    P.ecf1   = (const float*)d_in[12];
    P.ecb2   = (const float*)d_in[13];
    P.ecf2   = (const float*)d_in[14];
    P.wh     = (const float*)d_in[15];
    P.bh     = (const float*)d_in[16];
    P.out    = (float*)d_out;

    char* wsb = (char*)d_ws;
    size_t off = 0;
    auto take = [&](size_t bytes) -> char* {
        char* p = wsb + off;
        off = (off + bytes + 255) & ~(size_t)255;
        return p;
    };
    P.W16   = (bf16_t*)take(589824 * 2);
    P.SBN   = (float*)take(28 * 256 * 4);
    P.cnts  = (int*)take(256);
    P.indeg = (int*)take(2 * NSTRIDE * 4);
    P.rowst = (int*)take((2 * NSTRIDE + 64) * 4);
    P.curs  = (int*)take(2 * NSTRIDE * 4);
    P.psrc  = (int*)take(2 * (size_t)EPAD * 4);
    P.pdst  = (int*)take(2 * (size_t)EPAD * 4);
    P.U     = (float*)take((size_t)NPAD * C * 4);
    P.G0    = (bf16_t*)take((size_t)NPAD * C * 2);
    P.G1    = (bf16_t*)take((size_t)NPAD * C * 2);
    P.msg   = (bf16_t*)take((size_t)EPAD * C * 2);
    (void)ws_size; (void)in_sizes; (void)n_in; (void)out_size;

    hipMemsetAsync(P.indeg, 0, 2 * NSTRIDE * 4, stream);
    prep0<<<2787, 256, 0, stream>>>(P);
    scan_kernel<<<2, 1024, 0, stream>>>(P);
    combo0<<<783, 256, 0, stream>>>(P);
    for (int h = 0; h < 8; h++) {
        edge_k<<<EPAD / 64, 256, 0, stream>>>(P, h);
        aggk1<<<1250, 512, 0, stream>>>(P, h);
    }
}